// Round 3
// baseline (467.854 us; speedup 1.0000x reference)
//
#include <hip/hip_runtime.h>
#include <hip/hip_bf16.h>
#include <stdint.h>

// Problem dims (fixed by reference setup_inputs)
#define Mdim 8192   // B*S = 4*2048
#define Ndim 4096   // OUT
#define Kdim 4096   // IN

#define BM 128
#define BN 128
#define BK 64

typedef int v4i __attribute__((ext_vector_type(4)));

__device__ __forceinline__ void gload_lds16(const void* g, void* l) {
  __builtin_amdgcn_global_load_lds(
      (const __attribute__((address_space(1))) unsigned int*)g,
      (__attribute__((address_space(3))) unsigned int*)l,
      16 /*bytes*/, 0 /*offset*/, 0 /*aux*/);
}

// ---------------------------------------------------------------------------
// Kernel 1: quantize activations. xi = clip(rint((x*input_scale)*(1/act)))
// ---------------------------------------------------------------------------
__global__ void quant_x_kernel(const float* __restrict__ x,
                               const float* __restrict__ in_scale,
                               const float* __restrict__ act_scale_p,
                               int8_t* __restrict__ xq) {
  const float inv_act = 1.0f / (*act_scale_p);
  const int64_t tid = (int64_t)blockIdx.x * blockDim.x + threadIdx.x;
  const int64_t base = tid * 16;
  const int k0 = (int)(base & (Kdim - 1));  // Kdim is pow2
  const float4* xv = (const float4*)(x + base);
  const float4* sv = (const float4*)(in_scale + k0);
  alignas(16) int8_t ob[16];
#pragma unroll
  for (int j = 0; j < 4; ++j) {
    float4 xx = xv[j];
    float4 ss = sv[j];
    float r0 = rintf((xx.x * ss.x) * inv_act);
    float r1 = rintf((xx.y * ss.y) * inv_act);
    float r2 = rintf((xx.z * ss.z) * inv_act);
    float r3 = rintf((xx.w * ss.w) * inv_act);
    r0 = fminf(fmaxf(r0, -127.f), 127.f);
    r1 = fminf(fmaxf(r1, -127.f), 127.f);
    r2 = fminf(fmaxf(r2, -127.f), 127.f);
    r3 = fminf(fmaxf(r3, -127.f), 127.f);
    ob[j * 4 + 0] = (int8_t)r0;
    ob[j * 4 + 1] = (int8_t)r1;
    ob[j * 4 + 2] = (int8_t)r2;
    ob[j * 4 + 3] = (int8_t)r3;
  }
  *(v4i*)(xq + base) = *(const v4i*)ob;
}

// ---------------------------------------------------------------------------
// Kernel 2: pack int32 weights to int8 ([N,K] row-major kept as-is = B^T).
// ---------------------------------------------------------------------------
__global__ void pack_w_kernel(const int* __restrict__ w, int8_t* __restrict__ wq) {
  const int64_t tid = (int64_t)blockIdx.x * blockDim.x + threadIdx.x;
  const int64_t base = tid * 16;
  const int4* wv = (const int4*)(w + base);
  alignas(16) int8_t ob[16];
#pragma unroll
  for (int j = 0; j < 4; ++j) {
    int4 t = wv[j];
    ob[j * 4 + 0] = (int8_t)t.x;
    ob[j * 4 + 1] = (int8_t)t.y;
    ob[j * 4 + 2] = (int8_t)t.z;
    ob[j * 4 + 3] = (int8_t)t.w;
  }
  *(v4i*)(wq + base) = *(const v4i*)ob;
}

// ---------------------------------------------------------------------------
// Kernel 3: int8 GEMM, double-buffered LDS, ONE barrier per K-iteration.
//   - tile k+1's global_load_lds issued immediately after the barrier,
//     awaited only at the NEXT barrier -> full compute phase hides latency.
//   - Hazard: barrier implies lgkmcnt(0) drain, so prev iter's ds_reads on
//     the buffer being overwritten are complete. Safe with 2 buffers.
//   - LDS XOR swizzle (phys chunk = logical ^ ((row>>1)&3)): 0 bank conflicts.
// Epilogue: out = acc * (act_scale * w_scale[n]) + bias[n], fp32.
// ---------------------------------------------------------------------------
__global__ __launch_bounds__(256) void gemm_i8_kernel(
    const int8_t* __restrict__ Aq, const int8_t* __restrict__ Bq,
    const float* __restrict__ w_scale, const float* __restrict__ bias,
    const float* __restrict__ act_scale_p, float* __restrict__ out) {
  __shared__ alignas(16) int8_t As[2][BM * BK];  // 2 x 8 KB
  __shared__ alignas(16) int8_t Bs[2][BN * BK];  // 2 x 8 KB

  const int t = threadIdx.x;

  // 2-wide m supertile for B-tile L2 reuse.
  const int lin = blockIdx.x;                       // 0..2047
  const int within = lin & 63;
  const int m_blk = (lin >> 6) * 2 + (within & 1);  // 0..63
  const int n_blk = within >> 1;                    // 0..31
  const int m0 = m_blk * BM;
  const int n0 = n_blk * BN;

  // Staging: thread t fills LDS slot t*16 (row = t>>2, phys chunk = t&3).
  const int srow = t >> 2;                           // 0..63
  const int scol = ((t & 3) ^ ((t >> 3) & 3)) * 16;  // swizzled k-offset
  const int8_t* gA0 = Aq + (int64_t)(m0 + srow) * Kdim + scol;
  const int8_t* gA1 = gA0 + (int64_t)64 * Kdim;
  const int8_t* gB0 = Bq + (int64_t)(n0 + srow) * Kdim + scol;
  const int8_t* gB1 = gB0 + (int64_t)64 * Kdim;

  const int w = t >> 6;          // wave 0..3
  const int l = t & 63;          // lane
  const int wm = (w >> 1) * 64;  // wave's C-block row origin within tile
  const int wn = (w & 1) * 64;   // wave's C-block col origin
  const int lrow = l & 15;       // fragment row (m for A, n for B)
  const int lk = (((l >> 4) ^ ((l >> 1) & 3))) * 16;  // swizzled phys chunk

  v4i acc[4][4] = {};

  // Prologue: issue tile 0 into buffer 0 (awaited at first barrier).
  gload_lds16(gA0, As[0] + t * 16);
  gload_lds16(gA1, As[0] + 4096 + t * 16);
  gload_lds16(gB0, Bs[0] + t * 16);
  gload_lds16(gB1, Bs[0] + 4096 + t * 16);

  int buf = 0;
  for (int kt = 0; kt < Kdim; kt += BK) {
    __syncthreads();  // vmcnt(0)+lgkmcnt(0) drain: buf's loads landed,
                      // prev iter's ds_reads on buf^1 retired.
    if (kt + BK < Kdim) {
      const int nb = buf ^ 1;
      gload_lds16(gA0 + kt + BK, As[nb] + t * 16);
      gload_lds16(gA1 + kt + BK, As[nb] + 4096 + t * 16);
      gload_lds16(gB0 + kt + BK, Bs[nb] + t * 16);
      gload_lds16(gB1 + kt + BK, Bs[nb] + 4096 + t * 16);
    }

    v4i af[4], bf[4];
#pragma unroll
    for (int i = 0; i < 4; ++i) {
      af[i] = *(const v4i*)(As[buf] + (wm + i * 16 + lrow) * BK + lk);
      bf[i] = *(const v4i*)(Bs[buf] + (wn + i * 16 + lrow) * BK + lk);
    }
#pragma unroll
    for (int i = 0; i < 4; ++i) {
#pragma unroll
      for (int j = 0; j < 4; ++j) {
        acc[i][j] = __builtin_amdgcn_mfma_i32_16x16x64_i8(af[i], bf[j], acc[i][j], 0, 0, 0);
      }
    }
    buf ^= 1;
  }

  // Epilogue: D mapping col = lane&15, row = (lane>>4)*4 + reg
  const float act = *act_scale_p;
  const int rowbase = (l >> 4) * 4;
#pragma unroll
  for (int j = 0; j < 4; ++j) {
    const int n = n0 + wn + j * 16 + lrow;
    const float sc = act * w_scale[n];
    const float bs = bias[n];
#pragma unroll
    for (int i = 0; i < 4; ++i) {
      const int mb = m0 + wm + i * 16 + rowbase;
#pragma unroll
      for (int r = 0; r < 4; ++r) {
        out[(int64_t)(mb + r) * Ndim + n] = (float)acc[i][j][r] * sc + bs;
      }
    }
  }
}

// ---------------------------------------------------------------------------
extern "C" void kernel_launch(void* const* d_in, const int* in_sizes, int n_in,
                              void* d_out, int out_size, void* d_ws, size_t ws_size,
                              hipStream_t stream) {
  const float* x        = (const float*)d_in[0];
  const float* in_scale = (const float*)d_in[1];
  const float* actp     = (const float*)d_in[2];
  const int*   w_int    = (const int*)d_in[3];
  const float* w_scale  = (const float*)d_in[4];
  const float* bias     = (const float*)d_in[5];
  float* out = (float*)d_out;

  int8_t* Aq = (int8_t*)d_ws;                        // 32 MiB
  int8_t* Bq = (int8_t*)d_ws + (size_t)Mdim * Kdim;  // 16 MiB

  {
    const int64_t nthreads = (int64_t)Mdim * Kdim / 16;  // 2,097,152
    quant_x_kernel<<<(int)(nthreads / 256), 256, 0, stream>>>(x, in_scale, actp, Aq);
  }
  {
    const int64_t nthreads = (int64_t)Ndim * Kdim / 16;  // 1,048,576
    pack_w_kernel<<<(int)(nthreads / 256), 256, 0, stream>>>(w_int, Bq);
  }
  {
    gemm_i8_kernel<<<dim3(2048), 256, 0, stream>>>(Aq, Bq, w_scale, bias, actp, out);
  }
}

// Round 4
// 428.289 us; speedup vs baseline: 1.0924x; 1.0924x over previous
//
#include <hip/hip_runtime.h>
#include <hip/hip_bf16.h>
#include <stdint.h>

// Problem dims (fixed by reference setup_inputs)
#define Mdim 8192   // B*S = 4*2048
#define Ndim 4096   // OUT
#define Kdim 4096   // IN

#define BM 128
#define BN 128
#define BK 128      // two K=64 half-tiles, each in the proven R2 layout

typedef int v4i __attribute__((ext_vector_type(4)));

__device__ __forceinline__ void gload_lds16(const void* g, void* l) {
  __builtin_amdgcn_global_load_lds(
      (const __attribute__((address_space(1))) unsigned int*)g,
      (__attribute__((address_space(3))) unsigned int*)l,
      16 /*bytes*/, 0 /*offset*/, 0 /*aux*/);
}

// ---------------------------------------------------------------------------
// Kernel 1: quantize activations. xi = clip(rint((x*input_scale)*(1/act)))
// ---------------------------------------------------------------------------
__global__ void quant_x_kernel(const float* __restrict__ x,
                               const float* __restrict__ in_scale,
                               const float* __restrict__ act_scale_p,
                               int8_t* __restrict__ xq) {
  const float inv_act = 1.0f / (*act_scale_p);
  const int64_t tid = (int64_t)blockIdx.x * blockDim.x + threadIdx.x;
  const int64_t base = tid * 16;
  const int k0 = (int)(base & (Kdim - 1));  // Kdim is pow2
  const float4* xv = (const float4*)(x + base);
  const float4* sv = (const float4*)(in_scale + k0);
  alignas(16) int8_t ob[16];
#pragma unroll
  for (int j = 0; j < 4; ++j) {
    float4 xx = xv[j];
    float4 ss = sv[j];
    float r0 = rintf((xx.x * ss.x) * inv_act);
    float r1 = rintf((xx.y * ss.y) * inv_act);
    float r2 = rintf((xx.z * ss.z) * inv_act);
    float r3 = rintf((xx.w * ss.w) * inv_act);
    r0 = fminf(fmaxf(r0, -127.f), 127.f);
    r1 = fminf(fmaxf(r1, -127.f), 127.f);
    r2 = fminf(fmaxf(r2, -127.f), 127.f);
    r3 = fminf(fmaxf(r3, -127.f), 127.f);
    ob[j * 4 + 0] = (int8_t)r0;
    ob[j * 4 + 1] = (int8_t)r1;
    ob[j * 4 + 2] = (int8_t)r2;
    ob[j * 4 + 3] = (int8_t)r3;
  }
  *(v4i*)(xq + base) = *(const v4i*)ob;
}

// ---------------------------------------------------------------------------
// Kernel 2: pack int32 weights to int8 ([N,K] row-major kept as-is = B^T).
// ---------------------------------------------------------------------------
__global__ void pack_w_kernel(const int* __restrict__ w, int8_t* __restrict__ wq) {
  const int64_t tid = (int64_t)blockIdx.x * blockDim.x + threadIdx.x;
  const int64_t base = tid * 16;
  const int4* wv = (const int4*)(w + base);
  alignas(16) int8_t ob[16];
#pragma unroll
  for (int j = 0; j < 4; ++j) {
    int4 t = wv[j];
    ob[j * 4 + 0] = (int8_t)t.x;
    ob[j * 4 + 1] = (int8_t)t.y;
    ob[j * 4 + 2] = (int8_t)t.z;
    ob[j * 4 + 3] = (int8_t)t.w;
  }
  *(v4i*)(wq + base) = *(const v4i*)ob;
}

// ---------------------------------------------------------------------------
// Kernel 3: int8 GEMM. C[M,N] = Aq[M,K] . Bq[N,K]^T
// R2's proven 2-barrier structure, widened to BK=128 to HALVE barrier count:
// the ~400 cyc/barrier vmcnt drain is amortized over 2x MFMA work.
// BK=128 stored as two independent K=64 half-tiles in the R2 layout
// (64 B rows, XOR swizzle phys_chunk = logical ^ ((row>>1)&3)) -> 0 conflicts.
// Epilogue: out = acc * (act_scale * w_scale[n]) + bias[n], fp32.
// ---------------------------------------------------------------------------
__global__ __launch_bounds__(256) void gemm_i8_kernel(
    const int8_t* __restrict__ Aq, const int8_t* __restrict__ Bq,
    const float* __restrict__ w_scale, const float* __restrict__ bias,
    const float* __restrict__ act_scale_p, float* __restrict__ out) {
  __shared__ alignas(16) int8_t As[2][BM * 64];  // half-tiles: 2 x 8 KB
  __shared__ alignas(16) int8_t Bs[2][BN * 64];  // half-tiles: 2 x 8 KB

  const int t = threadIdx.x;

  // 2-wide m supertile for B-tile L2 reuse.
  const int lin = blockIdx.x;                       // 0..2047
  const int within = lin & 63;
  const int m_blk = (lin >> 6) * 2 + (within & 1);  // 0..63
  const int n_blk = within >> 1;                    // 0..31
  const int m0 = m_blk * BM;
  const int n0 = n_blk * BN;

  // Staging: thread t fills LDS slot t*16 (row = t>>2, phys chunk = t&3).
  const int srow = t >> 2;                           // 0..63
  const int scol = ((t & 3) ^ ((t >> 3) & 3)) * 16;  // swizzled k-offset
  const int8_t* gA0 = Aq + (int64_t)(m0 + srow) * Kdim + scol;
  const int8_t* gA1 = gA0 + (int64_t)64 * Kdim;
  const int8_t* gB0 = Bq + (int64_t)(n0 + srow) * Kdim + scol;
  const int8_t* gB1 = gB0 + (int64_t)64 * Kdim;

  const int w = t >> 6;          // wave 0..3
  const int l = t & 63;          // lane
  const int wm = (w >> 1) * 64;  // wave's C-block row origin within tile
  const int wn = (w & 1) * 64;   // wave's C-block col origin
  const int lrow = l & 15;       // fragment row (m for A, n for B)
  const int lk = (((l >> 4) ^ ((l >> 1) & 3))) * 16;  // swizzled phys chunk

  v4i acc[4][4] = {};

  for (int kt = 0; kt < Kdim; kt += BK) {
    // Stage both K=64 halves (8 DMAs), then one drain for all of them.
#pragma unroll
    for (int h = 0; h < 2; ++h) {
      const int ko = kt + h * 64;
      gload_lds16(gA0 + ko, As[h] + t * 16);
      gload_lds16(gA1 + ko, As[h] + 4096 + t * 16);
      gload_lds16(gB0 + ko, Bs[h] + t * 16);
      gload_lds16(gB1 + ko, Bs[h] + 4096 + t * 16);
    }
    __syncthreads();  // single vmcnt drain for 2x the compute below

#pragma unroll
    for (int h = 0; h < 2; ++h) {
      v4i af[4], bf[4];
#pragma unroll
      for (int i = 0; i < 4; ++i) {
        af[i] = *(const v4i*)(As[h] + (wm + i * 16 + lrow) * 64 + lk);
        bf[i] = *(const v4i*)(Bs[h] + (wn + i * 16 + lrow) * 64 + lk);
      }
#pragma unroll
      for (int i = 0; i < 4; ++i) {
#pragma unroll
        for (int j = 0; j < 4; ++j) {
          acc[i][j] = __builtin_amdgcn_mfma_i32_16x16x64_i8(af[i], bf[j], acc[i][j], 0, 0, 0);
        }
      }
    }
    __syncthreads();  // protect LDS before next stage overwrites
  }

  // Epilogue: D mapping col = lane&15, row = (lane>>4)*4 + reg
  const float act = *act_scale_p;
  const int rowbase = (l >> 4) * 4;
#pragma unroll
  for (int j = 0; j < 4; ++j) {
    const int n = n0 + wn + j * 16 + lrow;
    const float sc = act * w_scale[n];
    const float bs = bias[n];
#pragma unroll
    for (int i = 0; i < 4; ++i) {
      const int mb = m0 + wm + i * 16 + rowbase;
#pragma unroll
      for (int r = 0; r < 4; ++r) {
        out[(int64_t)(mb + r) * Ndim + n] = (float)acc[i][j][r] * sc + bs;
      }
    }
  }
}

// ---------------------------------------------------------------------------
extern "C" void kernel_launch(void* const* d_in, const int* in_sizes, int n_in,
                              void* d_out, int out_size, void* d_ws, size_t ws_size,
                              hipStream_t stream) {
  const float* x        = (const float*)d_in[0];
  const float* in_scale = (const float*)d_in[1];
  const float* actp     = (const float*)d_in[2];
  const int*   w_int    = (const int*)d_in[3];
  const float* w_scale  = (const float*)d_in[4];
  const float* bias     = (const float*)d_in[5];
  float* out = (float*)d_out;

  int8_t* Aq = (int8_t*)d_ws;                        // 32 MiB
  int8_t* Bq = (int8_t*)d_ws + (size_t)Mdim * Kdim;  // 16 MiB

  {
    const int64_t nthreads = (int64_t)Mdim * Kdim / 16;  // 2,097,152
    quant_x_kernel<<<(int)(nthreads / 256), 256, 0, stream>>>(x, in_scale, actp, Aq);
  }
  {
    const int64_t nthreads = (int64_t)Ndim * Kdim / 16;  // 1,048,576
    pack_w_kernel<<<(int)(nthreads / 256), 256, 0, stream>>>(w_int, Bq);
  }
  {
    gemm_i8_kernel<<<dim3(2048), 256, 0, stream>>>(Aq, Bq, w_scale, bias, actp, out);
  }
}